// Round 4
// baseline (483.848 us; speedup 1.0000x reference)
//
#include <hip/hip_runtime.h>
#include <hip/hip_bf16.h>
#include <stdint.h>

#define N_TOKENS   65536
#define IN_FEAT    512
#define OUT_FEAT   512
#define NUM_EXPERT 64
#define BM 128
#define BN 128
#define BK 32
#define K_STEPS (IN_FEAT / BK)   // 16
#define MAX_TILES 640            // true worst case: 512 + 64 = 576 tiles

// ws layout (int32 units), total footprint 139264 bytes:
//   [0..63]     counts
//   [64..127]   cursors
//   [128..192]  offsets (exclusive prefix, 65 entries)
//   [196]       dtype flag: 0 = buffers are bf16, 1 = buffers are fp32
//   [197]       tile_count
//   [200..1928) tiles: 3 ints each (expert, start, count), 576 entries
//   [2048..)    order as ushort[65536] (token ids sorted by expert) = 128 KB
#define WS_OFFS   128
#define WS_FLAG   196
#define WS_NTILES 197
#define WS_TILES  200
#define WS_ORDER  2048
#define WS_NEEDED (2048 * 4 + 131072)

typedef __attribute__((ext_vector_type(8))) short bf16x8;
typedef __attribute__((ext_vector_type(4))) float f32x4;

__device__ __forceinline__ float b2f(short v) {
    union { float f; unsigned u; } z;
    z.u = ((unsigned)(unsigned short)v) << 16;
    return z.f;
}

__device__ __forceinline__ unsigned pk2(float a, float b) {
    union { __hip_bfloat16 h; unsigned short u; } x, y;
    x.h = __float2bfloat16(a);
    y.h = __float2bfloat16(b);
    return ((unsigned)y.u << 16) | (unsigned)x.u;
}

// Classify inp's bit patterns: bf16-pair data has low-u16 exponent fields
// clustered in the "plausible magnitude" band; fp32 data's low-u16 is a
// uniform-random mantissa half. Data-dependent but data is fixed per run ->
// same flag every call (graph-capture safe).
__global__ void k_detect(const unsigned* __restrict__ inw, int* __restrict__ ws) {
    int lane = threadIdx.x;  // 64 threads, 1 wave
    int cnt = 0;
    #pragma unroll
    for (int i = 0; i < 16; ++i) {
        unsigned u = inw[lane * 16 + i];
        unsigned lo = u & 0xFFFFu;
        unsigned ec = (lo >> 7) & 0xFFu;       // bf16 exponent field of low half
        if (lo == 0u || (ec >= 90u && ec <= 131u)) cnt++;
    }
    #pragma unroll
    for (int d = 32; d > 0; d >>= 1) cnt += __shfl_down(cnt, d, 64);
    if (lane == 0) ws[WS_FLAG] = (cnt >= 512) ? 0 : 1;  // bf16 ~1000/1024, fp32 ~170/1024
}

__global__ void k_zero(int* ws) {
    int t = threadIdx.x;
    if (t < 128) ws[t] = 0;  // counts + cursors (does NOT touch WS_FLAG)
}

__global__ void k_hist(const int* __restrict__ gate, int* __restrict__ ws) {
    __shared__ int h[NUM_EXPERT];
    int t = threadIdx.x;
    if (t < NUM_EXPERT) h[t] = 0;
    __syncthreads();
    int base = blockIdx.x * 1024;
    #pragma unroll
    for (int k = 0; k < 4; ++k) {
        int g = gate[base + k * 256 + t] & 63;
        atomicAdd(&h[g], 1);
    }
    __syncthreads();
    if (t < NUM_EXPERT) atomicAdd(&ws[t], h[t]);
}

// single wave: prefix-scan counts, build tile descriptor list
__global__ void k_scan(int* ws) {
    int e = threadIdx.x;  // 0..63
    int c = ws[e];
    int pc = c;
    #pragma unroll
    for (int d = 1; d < 64; d <<= 1) {
        int v = __shfl_up(pc, d, 64);
        if (e >= d) pc += v;
    }
    int off = pc - c;  // exclusive prefix of token counts
    ws[WS_OFFS + e] = off;
    if (e == 63) ws[WS_OFFS + 64] = pc;

    int nt = (c + BM - 1) / BM;
    int tnt = nt;
    #pragma unroll
    for (int d = 1; d < 64; d <<= 1) {
        int v = __shfl_up(tnt, d, 64);
        if (e >= d) tnt += v;
    }
    int tbase = tnt - nt;
    for (int j = 0; j < nt; ++j) {
        int* t = ws + WS_TILES + (tbase + j) * 3;
        t[0] = e;
        t[1] = off + j * BM;
        int rem = c - j * BM;
        t[2] = rem < BM ? rem : BM;
    }
    if (e == 63) ws[WS_NTILES] = tnt;
}

__global__ void k_scatter(const int* __restrict__ gate, int* __restrict__ ws) {
    int* cursors = ws + 64;
    const int* offsets = ws + WS_OFFS;
    unsigned short* order = (unsigned short*)(ws + WS_ORDER);
    int t = threadIdx.x;
    int base = blockIdx.x * 1024;
    #pragma unroll
    for (int k = 0; k < 4; ++k) {
        int i = base + k * 256 + t;
        int e = gate[i] & 63;
        int pos = atomicAdd(&cursors[e], 1);
        unsigned idx = (unsigned)(offsets[e] + pos);
        if (idx < (unsigned)N_TOKENS) order[idx] = (unsigned short)i;
    }
}

// Grouped GEMM, templated on input/output dtype (FP32=1: fp32 buffers, convert
// to bf16 during staging; FP32=0: bf16 buffers). Early-exits on flag mismatch.
template <int FP32>
__global__ __launch_bounds__(256) void k_moe_gemm(
        const void* __restrict__ inp_,
        const void* __restrict__ weight_,
        void* __restrict__ out_,
        const int* __restrict__ ws) {
    __shared__ __align__(16) short sA[BM * BK];  // 8 KB (bf16 either way)
    __shared__ __align__(16) short sB[BN * BK];  // 8 KB
    __shared__ int sTok[BM];

    if (ws[WS_FLAG] != FP32) return;
    int ntiles = ws[WS_NTILES];
    if (ntiles > MAX_TILES) ntiles = MAX_TILES;
    int bx = blockIdx.x;
    if (bx >= ntiles) return;
    const int* tile = ws + WS_TILES + bx * 3;
    int e = tile[0] & 63;                      // defensive: in-bounds always
    int start = tile[1];
    int cnt = tile[2];
    cnt = cnt < 1 ? 1 : (cnt > BM ? BM : cnt);
    if (start < 0) start = 0;
    if (start > N_TOKENS - cnt) start = N_TOKENS - cnt;
    int n0 = blockIdx.y * BN;
    const unsigned short* order = (const unsigned short*)(ws + WS_ORDER);

    int tid = threadIdx.x;
    if (tid < BM) {
        int r = tid < cnt ? tid : (cnt - 1);
        sTok[tid] = (int)order[start + r];     // ushort -> always in [0,65535]
    }
    __syncthreads();

    int lane = tid & 63;
    int w = tid >> 6;
    int wm = (w >> 1) * 64;
    int wn = (w & 1) * 64;
    int l15 = lane & 15;
    int quad = lane >> 4;

    f32x4 acc[4][4];
    #pragma unroll
    for (int i = 0; i < 4; ++i)
        #pragma unroll
        for (int j = 0; j < 4; ++j)
            acc[i][j] = (f32x4){0.f, 0.f, 0.f, 0.f};

    const short* sAr = &sA[(wm + l15) * BK + quad * 8];
    const short* sBr = &sB[(wn + l15) * BK + quad * 8];

    if (FP32) {
        // staging: thread -> row ra (0..127), half h; 16 floats -> 16 bf16
        int ra = tid >> 1;
        int h = tid & 1;
        int tokA = sTok[ra];
        const float4* aG = (const float4*)((const float*)inp_ + (size_t)tokA * IN_FEAT) + h * 4;
        const float4* bG = (const float4*)((const float*)weight_ +
                           (size_t)(e * OUT_FEAT + n0 + ra) * IN_FEAT) + h * 4;
        uint4* sAd = (uint4*)&sA[ra * BK + h * 16];
        uint4* sBd = (uint4*)&sB[ra * BK + h * 16];

        for (int ks = 0; ks < K_STEPS; ++ks) {
            float4 a0 = aG[0], a1 = aG[1], a2 = aG[2], a3 = aG[3];
            float4 b0 = bG[0], b1 = bG[1], b2 = bG[2], b3 = bG[3];
            aG += 8; bG += 8;  // +BK floats
            __syncthreads();
            sAd[0] = (uint4){pk2(a0.x, a0.y), pk2(a0.z, a0.w), pk2(a1.x, a1.y), pk2(a1.z, a1.w)};
            sAd[1] = (uint4){pk2(a2.x, a2.y), pk2(a2.z, a2.w), pk2(a3.x, a3.y), pk2(a3.z, a3.w)};
            sBd[0] = (uint4){pk2(b0.x, b0.y), pk2(b0.z, b0.w), pk2(b1.x, b1.y), pk2(b1.z, b1.w)};
            sBd[1] = (uint4){pk2(b2.x, b2.y), pk2(b2.z, b2.w), pk2(b3.x, b3.y), pk2(b3.z, b3.w)};
            __syncthreads();

            bf16x8 a[4], b[4];
            #pragma unroll
            for (int t = 0; t < 4; ++t) {
                a[t] = *(const bf16x8*)(sAr + t * 16 * BK);
                b[t] = *(const bf16x8*)(sBr + t * 16 * BK);
            }
            #pragma unroll
            for (int i = 0; i < 4; ++i)
                #pragma unroll
                for (int j = 0; j < 4; ++j)
                    acc[i][j] = __builtin_amdgcn_mfma_f32_16x16x32_bf16(a[i], b[j], acc[i][j], 0, 0, 0);
        }
    } else {
        // staging: thread -> 16B chunk qc of rows rr and rr+64
        int rr = tid >> 2;
        int qc = tid & 3;
        int tokA0 = sTok[rr];
        int tokA1 = sTok[rr + 64];
        const uint4* aG0 = (const uint4*)((const short*)inp_ + (size_t)tokA0 * IN_FEAT) + qc;
        const uint4* aG1 = (const uint4*)((const short*)inp_ + (size_t)tokA1 * IN_FEAT) + qc;
        const uint4* bG0 = (const uint4*)((const short*)weight_ +
                           (size_t)(e * OUT_FEAT + n0 + rr) * IN_FEAT) + qc;
        const uint4* bG1 = (const uint4*)((const short*)weight_ +
                           (size_t)(e * OUT_FEAT + n0 + rr + 64) * IN_FEAT) + qc;
        uint4* sAd0 = (uint4*)&sA[tid * 8];
        uint4* sAd1 = (uint4*)&sA[(256 + tid) * 8];
        uint4* sBd0 = (uint4*)&sB[tid * 8];
        uint4* sBd1 = (uint4*)&sB[(256 + tid) * 8];

        for (int ks = 0; ks < K_STEPS; ++ks) {
            uint4 va0 = *aG0, va1 = *aG1, vb0 = *bG0, vb1 = *bG1;
            aG0 += 4; aG1 += 4; bG0 += 4; bG1 += 4;
            __syncthreads();
            *sAd0 = va0; *sAd1 = va1; *sBd0 = vb0; *sBd1 = vb1;
            __syncthreads();

            bf16x8 a[4], b[4];
            #pragma unroll
            for (int t = 0; t < 4; ++t) {
                a[t] = *(const bf16x8*)(sAr + t * 16 * BK);
                b[t] = *(const bf16x8*)(sBr + t * 16 * BK);
            }
            #pragma unroll
            for (int i = 0; i < 4; ++i)
                #pragma unroll
                for (int j = 0; j < 4; ++j)
                    acc[i][j] = __builtin_amdgcn_mfma_f32_16x16x32_bf16(a[i], b[j], acc[i][j], 0, 0, 0);
        }
    }

    // epilogue: D col = lane&15, row = quad*4 + reg  [m89/m91]
    #pragma unroll
    for (int i = 0; i < 4; ++i) {
        int mb = wm + i * 16 + quad * 4;
        #pragma unroll
        for (int r = 0; r < 4; ++r) {
            int m = mb + r;
            if (m < cnt) {
                int tok = sTok[m];
                if (FP32) {
                    float* orow = (float*)out_ + (size_t)tok * OUT_FEAT + n0 + wn + l15;
                    #pragma unroll
                    for (int j = 0; j < 4; ++j)
                        orow[j * 16] = acc[i][j][r];
                } else {
                    __hip_bfloat16* orow = (__hip_bfloat16*)out_ + (size_t)tok * OUT_FEAT + n0 + wn + l15;
                    #pragma unroll
                    for (int j = 0; j < 4; ++j)
                        orow[j * 16] = __float2bfloat16(acc[i][j][r]);
                }
            }
        }
    }
}

// ws-light fallback: one block per token, VALU dot products (only if ws too small)
template <int FP32>
__global__ __launch_bounds__(256) void k_gemv(
        const void* __restrict__ inp_,
        const int* __restrict__ gate,
        const void* __restrict__ weight_,
        void* __restrict__ out_,
        const int* __restrict__ ws) {
    if (ws[WS_FLAG] != FP32) return;
    __shared__ float xf[IN_FEAT];
    int t = threadIdx.x;
    int tok = blockIdx.x;
    int e = gate[tok] & 63;
    if (FP32) {
        const float* xr = (const float*)inp_ + (size_t)tok * IN_FEAT;
        xf[2 * t] = xr[2 * t];
        xf[2 * t + 1] = xr[2 * t + 1];
    } else {
        const short* xr = (const short*)inp_ + (size_t)tok * IN_FEAT;
        xf[2 * t] = b2f(xr[2 * t]);
        xf[2 * t + 1] = b2f(xr[2 * t + 1]);
    }
    __syncthreads();
    #pragma unroll
    for (int rep = 0; rep < 2; ++rep) {
        int o = t + rep * 256;
        float s = 0.f;
        if (FP32) {
            const float4* wr = (const float4*)((const float*)weight_ +
                               (size_t)(e * OUT_FEAT + o) * IN_FEAT);
            for (int k4 = 0; k4 < IN_FEAT / 4; ++k4) {
                float4 q = wr[k4];
                s += xf[4 * k4] * q.x + xf[4 * k4 + 1] * q.y
                   + xf[4 * k4 + 2] * q.z + xf[4 * k4 + 3] * q.w;
            }
            ((float*)out_)[(size_t)tok * OUT_FEAT + o] = s;
        } else {
            const short4* wr = (const short4*)((const short*)weight_ +
                               (size_t)(e * OUT_FEAT + o) * IN_FEAT);
            for (int k4 = 0; k4 < IN_FEAT / 4; ++k4) {
                short4 q = wr[k4];
                s += xf[4 * k4] * b2f(q.x) + xf[4 * k4 + 1] * b2f(q.y)
                   + xf[4 * k4 + 2] * b2f(q.z) + xf[4 * k4 + 3] * b2f(q.w);
            }
            ((__hip_bfloat16*)out_)[(size_t)tok * OUT_FEAT + o] = __float2bfloat16(s);
        }
    }
}

extern "C" void kernel_launch(void* const* d_in, const int* in_sizes, int n_in,
                              void* d_out, int out_size, void* d_ws, size_t ws_size,
                              hipStream_t stream) {
    const void* inp    = d_in[0];
    const int*  gate   = (const int*)d_in[1];
    const void* weight = d_in[2];
    int* ws = (int*)d_ws;

    k_detect<<<1, 64, 0, stream>>>((const unsigned*)inp, ws);
    if (ws_size >= (size_t)WS_NEEDED) {
        k_zero<<<1, 128, 0, stream>>>(ws);
        k_hist<<<64, 256, 0, stream>>>(gate, ws);
        k_scan<<<1, 64, 0, stream>>>(ws);
        k_scatter<<<64, 256, 0, stream>>>(gate, ws);
        dim3 grid(MAX_TILES, OUT_FEAT / BN);
        k_moe_gemm<0><<<grid, 256, 0, stream>>>(inp, weight, d_out, ws);
        k_moe_gemm<1><<<grid, 256, 0, stream>>>(inp, weight, d_out, ws);
    } else {
        k_gemv<0><<<N_TOKENS, 256, 0, stream>>>(inp, gate, weight, d_out, ws);
        k_gemv<1><<<N_TOKENS, 256, 0, stream>>>(inp, gate, weight, d_out, ws);
    }
}